// Round 1
// baseline (972.675 us; speedup 1.0000x reference)
//
#include <hip/hip_runtime.h>

// ---------------------------------------------------------------------------
// RNN_83313775608289: 4-layer tanh RNN (H=64) + FC, B=512, T=1024, D_in=52.
//   kernel 1 (pre0_kernel): pre0 = x @ Wih0^T + (bih0+bhh0) -> f16 [R][64]
//                           in d_ws (64 MiB). LDS-staged coalesced loads.
//   kernel 2 (rnn_pipe):    one block (8 waves, 512 thr) per PAIR of batch
//     rows (grid = B/2 = 256, 1 block/CU). Each wave runs its role for BOTH
//     rows per step -> 64 dot2/wave/step in 8 independent chains (ILP), and
//     half the barriers / LDS round-trips per row-step vs 1-row blocks.
//     wave 0: h0[t] = tanh(pre0[t] + Whh0 h0[t-1])            t = s
//     wave 1: P1[t] = Wih1 h0[t]                              t = s-1
//     wave 2: h1[t] = tanh(P1[t] + Whh1 h1[t-1] + b1)         t = s-2
//     wave 3: P2[t] = Wih2 h1[t]                              t = s-3
//     wave 4: h2[t] = tanh(P2[t] + Whh2 h2[t-1] + b2)         t = s-4
//     wave 5: P3[t] = Wih3 h2[t]                              t = s-5
//     wave 6: h3[t] = tanh(P3[t] + Whh3 h3[t-1] + b3)         t = s-6
//     wave 7: out[t] = Wfc h3[t] + bfc                        t = s-7
//   h handoff via LDS f16 rows (uniform ds_read_b128 broadcast -> v_dot2),
//   P handoff via LDS f32 per-lane. One barrier per step. 32 weight pairs
//   per wave (~60 VGPRs) so weights stay in arch VGPRs.
// ---------------------------------------------------------------------------

typedef __fp16 h2 __attribute__((ext_vector_type(2)));

__device__ __forceinline__ h2 pk2(float a, float b) {
#if __has_builtin(__builtin_amdgcn_cvt_pkrtz)
  return __builtin_amdgcn_cvt_pkrtz(a, b);
#else
  h2 r; r.x = (__fp16)a; r.y = (__fp16)b; return r;
#endif
}

__device__ __forceinline__ float fdot2f(h2 a, h2 b, float c) {
#if __has_builtin(__builtin_amdgcn_fdot2)
  return __builtin_amdgcn_fdot2(a, b, c, false);
#else
  return c + (float)a.x * (float)b.x + (float)a.y * (float)b.y;
#endif
}

__device__ __forceinline__ h2 bc(unsigned int u) {
  return __builtin_bit_cast(h2, u);
}

__device__ __forceinline__ float fast_tanh(float x) {
  float e = __expf(2.0f * x);          // overflow -> +inf -> result 1.0 (ok)
#if __has_builtin(__builtin_amdgcn_rcpf)
  return 1.0f - 2.0f * __builtin_amdgcn_rcpf(e + 1.0f);
#else
  return 1.0f - 2.0f / (e + 1.0f);
#endif
}

#define T_STEPS 1024

// ---------------------------------------------------------------------------
// Kernel 1: block = 256 thr handles 64 rows of x. Stage 64x52 f32 in LDS via
// coalesced float4, then each wave computes 16 rows: uniform float4 LDS reads
// (x pairs broadcast) x per-lane f16 weight pairs -> dot2.
// ---------------------------------------------------------------------------
__global__ __launch_bounds__(256) void pre0_kernel(
    const float* __restrict__ x, const float* __restrict__ Wih0,
    const float* __restrict__ bih0, const float* __restrict__ bhh0,
    __fp16* __restrict__ pre0h) {
  __shared__ float xs[64 * 52];  // 13312 B
  const int tid  = threadIdx.x;
  const int lane = tid & 63;
  const int wv   = tid >> 6;

  // coalesced tile copy: 64 rows * 52 f32 = 832 float4
  const float4* g4 = (const float4*)(x + (long)blockIdx.x * 64 * 52);
  float4* s4 = (float4*)xs;
#pragma unroll
  for (int i = 0; i < 4; ++i) {
    int idx = tid + i * 256;
    if (idx < 832) s4[idx] = g4[idx];
  }

  // lane j holds Wih0 row j as 26 f16 pairs
  h2 w[26];
  const float2* w2 = (const float2*)(Wih0 + lane * 52);
#pragma unroll
  for (int k = 0; k < 26; ++k) {
    float2 v = w2[k];
    w[k] = pk2(v.x, v.y);
  }
  const float bias = bih0[lane] + bhh0[lane];
  __syncthreads();

  const long obase = (long)blockIdx.x * 64;
#pragma unroll 1
  for (int r = wv * 16; r < wv * 16 + 16; ++r) {
    const float4* xr = (const float4*)(xs + r * 52);  // uniform per wave
    float a0 = bias, a1 = 0.f;
#pragma unroll
    for (int q = 0; q < 13; ++q) {
      float4 v = xr[q];
      a0 = fdot2f(pk2(v.x, v.y), w[2 * q],     a0);
      a1 = fdot2f(pk2(v.z, v.w), w[2 * q + 1], a1);
    }
    pre0h[(obase + r) * 64 + lane] = (__fp16)(a0 + a1);
  }
}

// ---------------------------------------------------------------------------
// Kernel 2: 8-wave pipelined scan, 2 batch rows per block. See header.
// ---------------------------------------------------------------------------
__global__ __launch_bounds__(512, 2) void rnn_pipe(
    const __fp16* __restrict__ pre0h, const float* __restrict__ Whh0,
    const float* __restrict__ Wih, const float* __restrict__ Whh,
    const float* __restrict__ bih, const float* __restrict__ bhh,
    const float* __restrict__ Wfc, const float* __restrict__ bfc,
    float* __restrict__ out) {
  const int tid  = threadIdx.x;
  const int lane = tid & 63;
  const int wv   = tid >> 6;  // 0..7

  __shared__ __attribute__((aligned(16))) __fp16 hbuf[4][2][2][64];  // 2 KiB
  __shared__ float Pbuf[3][2][2][64];                                // 3 KiB

  // zero-init h state: 4*2*2*64 f16 = 2048 B = 512 floats (== blockDim)
  ((float*)hbuf)[tid] = 0.f;

  // role/weights per wave
  // even wv (0,2,4,6): recurrent+tanh for layer L=wv/2 (weights Whh_L)
  // odd  wv (1,3,5):   input GEMV for layer L=(wv+1)/2 (weights Wih_L)
  // wv 7:              FC (weights Wfc)
  const float* W;
  float bias = 0.f;
  int role, L;
  if (wv == 7) {
    role = 2; L = 3; W = Wfc; bias = bfc[lane];
  } else if ((wv & 1) == 0) {
    role = 0; L = wv >> 1;
    W = (L == 0) ? Whh0 : (Whh + (L - 1) * 4096);
    if (L > 0) bias = bih[(L - 1) * 64 + lane] + bhh[(L - 1) * 64 + lane];
  } else {
    role = 1; L = (wv + 1) >> 1;
    W = Wih + (L - 1) * 4096;
  }

  h2 w[32];
  const float2* wsrc = (const float2*)(W + lane * 64);
#pragma unroll
  for (int k = 0; k < 32; ++k) {
    float2 v = wsrc[k];
    w[k] = pk2(v.x, v.y);
  }

  const long rb0 = (long)(blockIdx.x * 2) * T_STEPS;  // row pair
  const __fp16* pp0 = pre0h + rb0 * 64 + lane;
  const __fp16* pp1 = pp0 + (long)T_STEPS * 64;
  float* op0 = out + rb0 * 64 + lane;
  float* op1 = op0 + (long)T_STEPS * 64;

  float pcur0 = 0.f, pcur1 = 0.f;
  if (wv == 0) { pcur0 = (float)pp0[0]; pcur1 = (float)pp1[0]; }

  __syncthreads();

  for (int s = 0; s < T_STEPS + 7; ++s) {
    const int t  = s - wv;
    const int rd = (s - 1) & 1;
    const int wr = s & 1;
    if (t >= 0 && t < T_STEPS) {
      if (role == 0) {
        // h_L[t] = tanh( part + Whh_L * h_L[t-1] + bias ), both rows
        const uint4* hb0 = (const uint4*)hbuf[L][rd][0];  // uniform broadcast
        const uint4* hb1 = (const uint4*)hbuf[L][rd][1];
        float a0 = bias, a1 = 0.f, a2 = 0.f, a3 = 0.f;
        float c0 = bias, c1 = 0.f, c2 = 0.f, c3 = 0.f;
#pragma unroll
        for (int q = 0; q < 8; ++q) {
          uint4 u = hb0[q];
          uint4 v = hb1[q];
          a0 = fdot2f(bc(u.x), w[4 * q + 0], a0);
          a1 = fdot2f(bc(u.y), w[4 * q + 1], a1);
          a2 = fdot2f(bc(u.z), w[4 * q + 2], a2);
          a3 = fdot2f(bc(u.w), w[4 * q + 3], a3);
          c0 = fdot2f(bc(v.x), w[4 * q + 0], c0);
          c1 = fdot2f(bc(v.y), w[4 * q + 1], c1);
          c2 = fdot2f(bc(v.z), w[4 * q + 2], c2);
          c3 = fdot2f(bc(v.w), w[4 * q + 3], c3);
        }
        float part0, part1;
        if (L == 0) {
          part0 = pcur0;
          part1 = pcur1;
          pp0 += 64;
          pp1 += 64;
          if (t + 1 < T_STEPS) {  // prefetch next p for both rows
            pcur0 = (float)pp0[0];
            pcur1 = (float)pp1[0];
          }
        } else {
          part0 = Pbuf[L - 1][rd][0][lane];
          part1 = Pbuf[L - 1][rd][1][lane];
        }
        float h0 = fast_tanh(((a0 + a1) + (a2 + a3)) + part0);
        float h1 = fast_tanh(((c0 + c1) + (c2 + c3)) + part1);
        hbuf[L][wr][0][lane] = (__fp16)h0;
        hbuf[L][wr][1][lane] = (__fp16)h1;
      } else if (role == 1) {
        // P_L[t] = Wih_L * h_{L-1}[t], both rows
        const uint4* hb0 = (const uint4*)hbuf[L - 1][rd][0];
        const uint4* hb1 = (const uint4*)hbuf[L - 1][rd][1];
        float a0 = 0.f, a1 = 0.f, a2 = 0.f, a3 = 0.f;
        float c0 = 0.f, c1 = 0.f, c2 = 0.f, c3 = 0.f;
#pragma unroll
        for (int q = 0; q < 8; ++q) {
          uint4 u = hb0[q];
          uint4 v = hb1[q];
          a0 = fdot2f(bc(u.x), w[4 * q + 0], a0);
          a1 = fdot2f(bc(u.y), w[4 * q + 1], a1);
          a2 = fdot2f(bc(u.z), w[4 * q + 2], a2);
          a3 = fdot2f(bc(u.w), w[4 * q + 3], a3);
          c0 = fdot2f(bc(v.x), w[4 * q + 0], c0);
          c1 = fdot2f(bc(v.y), w[4 * q + 1], c1);
          c2 = fdot2f(bc(v.z), w[4 * q + 2], c2);
          c3 = fdot2f(bc(v.w), w[4 * q + 3], c3);
        }
        Pbuf[L - 1][wr][0][lane] = (a0 + a1) + (a2 + a3);
        Pbuf[L - 1][wr][1][lane] = (c0 + c1) + (c2 + c3);
      } else {
        // out[t] = Wfc * h3[t] + bfc, both rows
        const uint4* hb0 = (const uint4*)hbuf[3][rd][0];
        const uint4* hb1 = (const uint4*)hbuf[3][rd][1];
        float a0 = bias, a1 = 0.f, a2 = 0.f, a3 = 0.f;
        float c0 = bias, c1 = 0.f, c2 = 0.f, c3 = 0.f;
#pragma unroll
        for (int q = 0; q < 8; ++q) {
          uint4 u = hb0[q];
          uint4 v = hb1[q];
          a0 = fdot2f(bc(u.x), w[4 * q + 0], a0);
          a1 = fdot2f(bc(u.y), w[4 * q + 1], a1);
          a2 = fdot2f(bc(u.z), w[4 * q + 2], a2);
          a3 = fdot2f(bc(u.w), w[4 * q + 3], a3);
          c0 = fdot2f(bc(v.x), w[4 * q + 0], c0);
          c1 = fdot2f(bc(v.y), w[4 * q + 1], c1);
          c2 = fdot2f(bc(v.z), w[4 * q + 2], c2);
          c3 = fdot2f(bc(v.w), w[4 * q + 3], c3);
        }
        op0[0] = (a0 + a1) + (a2 + a3);
        op1[0] = (c0 + c1) + (c2 + c3);
        op0 += 64;
        op1 += 64;
      }
    }
    __syncthreads();  // uniform: every thread, every step
  }
}

// ---------------------------------------------------------------------------
extern "C" void kernel_launch(void* const* d_in, const int* in_sizes, int n_in,
                              void* d_out, int out_size, void* d_ws,
                              size_t ws_size, hipStream_t stream) {
  const float* x    = (const float*)d_in[0];
  const float* Wih0 = (const float*)d_in[1];
  const float* Whh0 = (const float*)d_in[2];
  const float* bih0 = (const float*)d_in[3];
  const float* bhh0 = (const float*)d_in[4];
  const float* Wih  = (const float*)d_in[5];
  const float* Whh  = (const float*)d_in[6];
  const float* bih  = (const float*)d_in[7];
  const float* bhh  = (const float*)d_in[8];
  const float* Wfc  = (const float*)d_in[9];
  const float* bfc  = (const float*)d_in[10];
  float* out = (float*)d_out;

  const int B = in_sizes[0] / (T_STEPS * 52);  // 512
  const int R = B * T_STEPS;

  __fp16* pre0h = (__fp16*)d_ws;  // R*64 f16 = 64 MiB

  pre0_kernel<<<R / 64, 256, 0, stream>>>(x, Wih0, bih0, bhh0, pre0h);
  rnn_pipe<<<B / 2, 512, 0, stream>>>(pre0h, Whh0, Wih, Whh, bih, bhh, Wfc,
                                      bfc, out);
}

// Round 2
// 737.448 us; speedup vs baseline: 1.3190x; 1.3190x over previous
//
#include <hip/hip_runtime.h>

// ---------------------------------------------------------------------------
// RNN_83313775608289: 4-layer tanh RNN (H=64) + FC, B=512, T=1024, D_in=52.
//   kernel 1 (pre0_kernel): pre0 = x @ Wih0^T + (bih0+bhh0), packed as
//     PAIRED f16 (t even, t odd) dwords -> u32 [B][T/2][64] in d_ws (64 MiB).
//   kernel 2 (rnn_pipe): one block (8 waves) per batch row, 512 blocks =
//     2 blocks/CU (round-0 structure, which benched best). NEW: each barrier
//     interval advances TWO time steps (519 intervals vs 1031):
//       wave 0: h0[t0],h0[t1] = tanh(pre0 + Whh0 h0[.-1])   t0 = 2(k-0)
//       wave 1: P1[t0],P1[t1] = Wih1 h0[.]                  t0 = 2(k-1)
//       wave 2: h1[..]        = tanh(P1 + Whh1 h1[.-1] + b) t0 = 2(k-2)
//       ... (same skew pattern, FC at wave 7, t0 = 2(k-7))
//     Recurrent waves chain step 2 through an intra-wave LDS write->readback
//     (lgkmcnt only, no barrier). Odd/FC waves do two INDEPENDENT GEMVs per
//     interval (16 dot chains -> ILP). Halves barrier + loop overhead per
//     step; pre0 pair-load is one dword per interval.
// ---------------------------------------------------------------------------

typedef __fp16 h2 __attribute__((ext_vector_type(2)));

__device__ __forceinline__ h2 pk2(float a, float b) {
#if __has_builtin(__builtin_amdgcn_cvt_pkrtz)
  return __builtin_amdgcn_cvt_pkrtz(a, b);
#else
  h2 r; r.x = (__fp16)a; r.y = (__fp16)b; return r;
#endif
}

__device__ __forceinline__ float fdot2f(h2 a, h2 b, float c) {
#if __has_builtin(__builtin_amdgcn_fdot2)
  return __builtin_amdgcn_fdot2(a, b, c, false);
#else
  return c + (float)a.x * (float)b.x + (float)a.y * (float)b.y;
#endif
}

__device__ __forceinline__ h2 bc(unsigned int u) {
  return __builtin_bit_cast(h2, u);
}

__device__ __forceinline__ float fast_tanh(float x) {
  float e = __expf(2.0f * x);          // overflow -> +inf -> result 1.0 (ok)
#if __has_builtin(__builtin_amdgcn_rcpf)
  return 1.0f - 2.0f * __builtin_amdgcn_rcpf(e + 1.0f);
#else
  return 1.0f - 2.0f / (e + 1.0f);
#endif
}

#define T_STEPS 1024

// ---------------------------------------------------------------------------
// Kernel 1: block = 256 thr handles 64 rows of x (one batch b, 64 t's).
// Stage 64x52 f32 in LDS, each wave computes 8 ROW PAIRS (t even, t odd) and
// stores one packed f16x2 dword per lane -> dense coalesced dword stores.
// ---------------------------------------------------------------------------
__global__ __launch_bounds__(256) void pre0_kernel(
    const float* __restrict__ x, const float* __restrict__ Wih0,
    const float* __restrict__ bih0, const float* __restrict__ bhh0,
    unsigned int* __restrict__ pre0p) {
  __shared__ float xs[64 * 52];  // 13312 B
  const int tid  = threadIdx.x;
  const int lane = tid & 63;
  const int wv   = tid >> 6;

  // coalesced tile copy: 64 rows * 52 f32 = 832 float4
  const float4* g4 = (const float4*)(x + (long)blockIdx.x * 64 * 52);
  float4* s4 = (float4*)xs;
#pragma unroll
  for (int i = 0; i < 4; ++i) {
    int idx = tid + i * 256;
    if (idx < 832) s4[idx] = g4[idx];
  }

  // lane j holds Wih0 row j as 26 f16 pairs
  h2 w[26];
  const float2* w2 = (const float2*)(Wih0 + lane * 52);
#pragma unroll
  for (int k = 0; k < 26; ++k) {
    float2 v = w2[k];
    w[k] = pk2(v.x, v.y);
  }
  const float bias = bih0[lane] + bhh0[lane];
  __syncthreads();

  const long obase = (long)blockIdx.x * 64;  // flat row base (64-aligned)
#pragma unroll 1
  for (int rp = wv * 8; rp < wv * 8 + 8; ++rp) {
    const int r0 = rp * 2;  // even flat row within block
    const float4* xr0 = (const float4*)(xs + r0 * 52);       // 208B stride,
    const float4* xr1 = (const float4*)(xs + r0 * 52 + 52);  // 16B-aligned
    float a0 = bias, a1 = 0.f, c0 = bias, c1 = 0.f;
#pragma unroll
    for (int q = 0; q < 13; ++q) {
      float4 u = xr0[q];
      float4 v = xr1[q];
      a0 = fdot2f(pk2(u.x, u.y), w[2 * q],     a0);
      a1 = fdot2f(pk2(u.z, u.w), w[2 * q + 1], a1);
      c0 = fdot2f(pk2(v.x, v.y), w[2 * q],     c0);
      c1 = fdot2f(pk2(v.z, v.w), w[2 * q + 1], c1);
    }
    // flat pair index = (b*1024 + t) >> 1 = b*512 + t/2
    pre0p[((obase + r0) >> 1) * 64 + lane] =
        __builtin_bit_cast(unsigned int, pk2(a0 + a1, c0 + c1));
  }
}

// ---------------------------------------------------------------------------
// Kernel 2: 8-wave pipelined scan, 2 TIME STEPS per barrier interval.
// ---------------------------------------------------------------------------
__global__ __launch_bounds__(512, 4) void rnn_pipe(
    const unsigned int* __restrict__ pre0p, const float* __restrict__ Whh0,
    const float* __restrict__ Wih, const float* __restrict__ Whh,
    const float* __restrict__ bih, const float* __restrict__ bhh,
    const float* __restrict__ Wfc, const float* __restrict__ bfc,
    float* __restrict__ out) {
  const int tid  = threadIdx.x;
  const int lane = tid & 63;
  const int wv   = tid >> 6;  // 0..7
  const int b    = blockIdx.x;

  // [layer][interval-slot][step-within-interval][lane]
  __shared__ __attribute__((aligned(16))) __fp16 hbuf[4][2][2][64];  // 2 KiB
  __shared__ float Pbuf[3][2][2][64];                                // 3 KiB

  // zero-init hbuf (h[t=-1] = 0): 4*2*2*64 f16 = 512 floats = blockDim
  ((float*)hbuf)[tid] = 0.f;

  // role/weights per wave (same mapping as round-0)
  const float* W;
  float bias = 0.f;
  int role, L;
  if (wv == 7) {
    role = 2; L = 3; W = Wfc; bias = bfc[lane];
  } else if ((wv & 1) == 0) {
    role = 0; L = wv >> 1;
    W = (L == 0) ? Whh0 : (Whh + (L - 1) * 4096);
    if (L > 0) bias = bih[(L - 1) * 64 + lane] + bhh[(L - 1) * 64 + lane];
  } else {
    role = 1; L = (wv + 1) >> 1;
    W = Wih + (L - 1) * 4096;
  }

  h2 w[32];
  const float2* wsrc = (const float2*)(W + lane * 64);
#pragma unroll
  for (int k = 0; k < 32; ++k) {
    float2 v = wsrc[k];
    w[k] = pk2(v.x, v.y);
  }

  const long rowbase = (long)b * T_STEPS;
  const unsigned int* pp = pre0p + (long)b * 512 * 64 + lane;  // paired pre0
  float* op = out + rowbase * 64 + lane;

  unsigned int pc = 0;
  if (wv == 0) pc = pp[0];  // prefetch pre pair for t={0,1}

  __syncthreads();

#pragma unroll 1
  for (int k = 0; k < 512 + 7; ++k) {
    const unsigned kk = (unsigned)(k - wv);  // interval index for this wave
    const int rd = (k - 1) & 1;
    const int wr = k & 1;
    if (kk < 512u) {
      if (role == 0) {
        // ---- step t0 = 2*kk: h_L[t0] = tanh(part0 + Whh_L h_L[t0-1] + b)
        const uint4* hprev = (const uint4*)hbuf[L][rd][1];  // h[t0-1]
        float a0 = bias, a1 = 0.f, a2 = 0.f, a3 = 0.f;
#pragma unroll
        for (int q = 0; q < 8; ++q) {
          uint4 u = hprev[q];
          a0 = fdot2f(bc(u.x), w[4 * q + 0], a0);
          a1 = fdot2f(bc(u.y), w[4 * q + 1], a1);
          a2 = fdot2f(bc(u.z), w[4 * q + 2], a2);
          a3 = fdot2f(bc(u.w), w[4 * q + 3], a3);
        }
        float part0, part1;
        if (L == 0) {
          h2 pv = bc(pc);
          part0 = (float)pv.x;
          part1 = (float)pv.y;
          pp += 64;
          if (kk + 1 < 512u) pc = pp[0];  // prefetch next interval's pair
        } else {
          part0 = Pbuf[L - 1][rd][0][lane];
          part1 = Pbuf[L - 1][rd][1][lane];
        }
        float h0v = fast_tanh(((a0 + a1) + (a2 + a3)) + part0);
        hbuf[L][wr][0][lane] = (__fp16)h0v;
        // ---- step t1 = t0+1: needs full h[t0] -> intra-wave LDS readback
        const uint4* hcur = (const uint4*)hbuf[L][wr][0];
        float c0 = bias, c1 = 0.f, c2 = 0.f, c3 = 0.f;
#pragma unroll
        for (int q = 0; q < 8; ++q) {
          uint4 v = hcur[q];
          c0 = fdot2f(bc(v.x), w[4 * q + 0], c0);
          c1 = fdot2f(bc(v.y), w[4 * q + 1], c1);
          c2 = fdot2f(bc(v.z), w[4 * q + 2], c2);
          c3 = fdot2f(bc(v.w), w[4 * q + 3], c3);
        }
        float h1v = fast_tanh(((c0 + c1) + (c2 + c3)) + part1);
        hbuf[L][wr][1][lane] = (__fp16)h1v;
      } else if (role == 1) {
        // P_L[t0], P_L[t1] = Wih_L h_{L-1}[t0], h_{L-1}[t1] — independent
        const uint4* h0p = (const uint4*)hbuf[L - 1][rd][0];
        const uint4* h1p = (const uint4*)hbuf[L - 1][rd][1];
        float a0 = 0.f, a1 = 0.f, a2 = 0.f, a3 = 0.f;
        float c0 = 0.f, c1 = 0.f, c2 = 0.f, c3 = 0.f;
#pragma unroll
        for (int q = 0; q < 8; ++q) {
          uint4 u = h0p[q];
          uint4 v = h1p[q];
          a0 = fdot2f(bc(u.x), w[4 * q + 0], a0);
          a1 = fdot2f(bc(u.y), w[4 * q + 1], a1);
          a2 = fdot2f(bc(u.z), w[4 * q + 2], a2);
          a3 = fdot2f(bc(u.w), w[4 * q + 3], a3);
          c0 = fdot2f(bc(v.x), w[4 * q + 0], c0);
          c1 = fdot2f(bc(v.y), w[4 * q + 1], c1);
          c2 = fdot2f(bc(v.z), w[4 * q + 2], c2);
          c3 = fdot2f(bc(v.w), w[4 * q + 3], c3);
        }
        Pbuf[L - 1][wr][0][lane] = (a0 + a1) + (a2 + a3);
        Pbuf[L - 1][wr][1][lane] = (c0 + c1) + (c2 + c3);
      } else {
        // out[t0], out[t1] = Wfc h3[.] + bfc — independent
        const uint4* h0p = (const uint4*)hbuf[3][rd][0];
        const uint4* h1p = (const uint4*)hbuf[3][rd][1];
        float a0 = bias, a1 = 0.f, a2 = 0.f, a3 = 0.f;
        float c0 = bias, c1 = 0.f, c2 = 0.f, c3 = 0.f;
#pragma unroll
        for (int q = 0; q < 8; ++q) {
          uint4 u = h0p[q];
          uint4 v = h1p[q];
          a0 = fdot2f(bc(u.x), w[4 * q + 0], a0);
          a1 = fdot2f(bc(u.y), w[4 * q + 1], a1);
          a2 = fdot2f(bc(u.z), w[4 * q + 2], a2);
          a3 = fdot2f(bc(u.w), w[4 * q + 3], a3);
          c0 = fdot2f(bc(v.x), w[4 * q + 0], c0);
          c1 = fdot2f(bc(v.y), w[4 * q + 1], c1);
          c2 = fdot2f(bc(v.z), w[4 * q + 2], c2);
          c3 = fdot2f(bc(v.w), w[4 * q + 3], c3);
        }
        op[0]  = (a0 + a1) + (a2 + a3);
        op[64] = (c0 + c1) + (c2 + c3);
        op += 128;
      }
    }
    __syncthreads();  // uniform: every thread, every interval
  }
}

// ---------------------------------------------------------------------------
extern "C" void kernel_launch(void* const* d_in, const int* in_sizes, int n_in,
                              void* d_out, int out_size, void* d_ws,
                              size_t ws_size, hipStream_t stream) {
  const float* x    = (const float*)d_in[0];
  const float* Wih0 = (const float*)d_in[1];
  const float* Whh0 = (const float*)d_in[2];
  const float* bih0 = (const float*)d_in[3];
  const float* bhh0 = (const float*)d_in[4];
  const float* Wih  = (const float*)d_in[5];
  const float* Whh  = (const float*)d_in[6];
  const float* bih  = (const float*)d_in[7];
  const float* bhh  = (const float*)d_in[8];
  const float* Wfc  = (const float*)d_in[9];
  const float* bfc  = (const float*)d_in[10];
  float* out = (float*)d_out;

  const int B = in_sizes[0] / (T_STEPS * 52);  // 512
  const int R = B * T_STEPS;

  unsigned int* pre0p = (unsigned int*)d_ws;  // R/2 * 64 u32 = 64 MiB

  pre0_kernel<<<R / 64, 256, 0, stream>>>(x, Wih0, bih0, bhh0, pre0p);
  rnn_pipe<<<B, 512, 0, stream>>>(pre0p, Whh0, Wih, Whh, bih, bhh, Wfc, bfc,
                                  out);
}

// Round 4
// 674.340 us; speedup vs baseline: 1.4424x; 1.0936x over previous
//
#include <hip/hip_runtime.h>

// ---------------------------------------------------------------------------
// RNN_83313775608289: 4-layer tanh RNN (H=64) + FC, B=512, T=1024, D_in=52.
//   kernel 1 (pre0_kernel): pre0 = x @ Wih0^T + (bih0+bhh0), packed as
//     PAIRED f16 (t even, t odd) dwords -> u32 [B][T/2][64] in d_ws (64 MiB).
//     r3: copy-convert BOTH x-tile and Wih0 to f16 pairs in LDS via
//     coalesced float4 loads (the old per-lane strided Wih0 load was 64
//     cachelines/instr = ~90us chip-wide; the old per-row pk2 of x doubled
//     main-loop VALU). Main loop: 13 uniform ds_read_b128 + 52 dot2 per
//     row-pair.
//   kernel 2 (rnn_pipe): one block (8 waves) per batch row, 512 blocks =
//     2 blocks/CU. r3: FOUR time steps per barrier interval (263 intervals
//     vs 519) — measured overhead is ~575 cy/interval, so halving intervals
//     again buys ~10%. Recurrent waves chain steps through intra-wave LDS
//     readback (lgkmcnt only); odd/FC waves do 4 independent GEMVs (16 dot
//     chains of ILP). wv scalarized via readfirstlane so guards are SALU.
//       wave 0: h0[4k..4k+3] = tanh(pre0 + Whh0 h0[.-1])   k' = k-0
//       wave 1: P1[..] = Wih1 h0[..]                       k' = k-1
//       wave 2: h1[..] = tanh(P1 + Whh1 h1[.-1] + b1)      k' = k-2
//       ...                                                 (skew 1/wave)
//       wave 7: out[..] = Wfc h3[..] + bfc                 k' = k-7
// ---------------------------------------------------------------------------

typedef __fp16 h2 __attribute__((ext_vector_type(2)));

__device__ __forceinline__ h2 pk2(float a, float b) {
#if __has_builtin(__builtin_amdgcn_cvt_pkrtz)
  return __builtin_amdgcn_cvt_pkrtz(a, b);
#else
  h2 r; r.x = (__fp16)a; r.y = (__fp16)b; return r;
#endif
}

__device__ __forceinline__ float fdot2f(h2 a, h2 b, float c) {
#if __has_builtin(__builtin_amdgcn_fdot2)
  return __builtin_amdgcn_fdot2(a, b, c, false);
#else
  return c + (float)a.x * (float)b.x + (float)a.y * (float)b.y;
#endif
}

__device__ __forceinline__ h2 bc(unsigned int u) {
  return __builtin_bit_cast(h2, u);
}

__device__ __forceinline__ float fast_tanh(float x) {
  float e = __expf(2.0f * x);          // overflow -> +inf -> result 1.0 (ok)
#if __has_builtin(__builtin_amdgcn_rcpf)
  return 1.0f - 2.0f * __builtin_amdgcn_rcpf(e + 1.0f);
#else
  return 1.0f - 2.0f / (e + 1.0f);
#endif
}

#define T_STEPS 1024

// ---------------------------------------------------------------------------
// Kernel 1: block = 256 thr handles 64 rows of x (one batch b, 64 t's).
// ---------------------------------------------------------------------------
// accumulate pair J (0..51) of a row-pair: row0 if J<26 (weight w[J]),
// row1 otherwise (weight w[J-26]). J is compile-time after unroll.
#define ACC(U, J)                                         \
  do {                                                    \
    h2 hv_ = bc(U);                                       \
    if ((J) < 26) {                                       \
      if ((J) & 1) a1 = fdot2f(hv_, w[(J)], a1);          \
      else         a0 = fdot2f(hv_, w[(J)], a0);          \
    } else {                                              \
      if ((J) & 1) c1 = fdot2f(hv_, w[(J) - 26], c1);     \
      else         c0 = fdot2f(hv_, w[(J) - 26], c0);     \
    }                                                     \
  } while (0)

__global__ __launch_bounds__(256) void pre0_kernel(
    const float* __restrict__ x, const float* __restrict__ Wih0,
    const float* __restrict__ bih0, const float* __restrict__ bhh0,
    unsigned int* __restrict__ pre0p) {
  __shared__ unsigned int xsh[64 * 26];  // x tile as f16 pairs, 6656 B
  __shared__ unsigned int wsh[64 * 26];  // Wih0 as f16 pairs, 6656 B
  const int tid  = threadIdx.x;
  const int lane = tid & 63;
  const int wv   = tid >> 6;

  // coalesced copy-convert: 832 float4 each for x tile and Wih0
  const float4* xg = (const float4*)(x + (long)blockIdx.x * 64 * 52);
  const float4* wg = (const float4*)Wih0;
#pragma unroll
  for (int i = 0; i < 4; ++i) {
    int idx = tid + i * 256;
    if (idx < 832) {
      float4 v = xg[idx];
      xsh[idx * 2]     = __builtin_bit_cast(unsigned int, pk2(v.x, v.y));
      xsh[idx * 2 + 1] = __builtin_bit_cast(unsigned int, pk2(v.z, v.w));
      float4 u = wg[idx];
      wsh[idx * 2]     = __builtin_bit_cast(unsigned int, pk2(u.x, u.y));
      wsh[idx * 2 + 1] = __builtin_bit_cast(unsigned int, pk2(u.z, u.w));
    }
  }
  const float bias = bih0[lane] + bhh0[lane];
  __syncthreads();

  // lane j holds Wih0 row j as 26 f16 pairs (one-time LDS read)
  h2 w[26];
  {
    const uint2* wr2 = (const uint2*)(wsh + lane * 26);
#pragma unroll
    for (int k = 0; k < 13; ++k) {
      uint2 u = wr2[k];
      w[2 * k]     = bc(u.x);
      w[2 * k + 1] = bc(u.y);
    }
  }

  const long pbase = (long)blockIdx.x * 32;  // flat pair base
#pragma unroll 1
  for (int rp = wv * 8; rp < wv * 8 + 8; ++rp) {
    // row-pair rp covers rows 2rp,2rp+1 = 52 contiguous dwords, 208B-aligned
    const uint4* xp = (const uint4*)(xsh + rp * 52);
    float a0 = bias, a1 = 0.f, c0 = bias, c1 = 0.f;
#pragma unroll
    for (int q = 0; q < 13; ++q) {
      uint4 v = xp[q];
      ACC(v.x, 4 * q + 0);
      ACC(v.y, 4 * q + 1);
      ACC(v.z, 4 * q + 2);
      ACC(v.w, 4 * q + 3);
    }
    pre0p[(pbase + rp) * 64 + lane] =
        __builtin_bit_cast(unsigned int, pk2(a0 + a1, c0 + c1));
  }
}

// ---------------------------------------------------------------------------
// Kernel 2: 8-wave pipelined scan, 4 TIME STEPS per barrier interval.
// ---------------------------------------------------------------------------
// 64-wide GEMV: 8 uniform ds_read_b128 + 32 dot2 in 4 chains. Macro (not fn)
// so w[] (read from enclosing scope) stays compile-time-indexed -> registers.
#define GEMV64(RES, HPTR, INIT)                               \
  do {                                                        \
    const uint4* hp_ = (const uint4*)(HPTR);                  \
    float a0_ = (INIT), a1_ = 0.f, a2_ = 0.f, a3_ = 0.f;      \
    _Pragma("unroll")                                         \
    for (int q_ = 0; q_ < 8; ++q_) {                          \
      uint4 u_ = hp_[q_];                                     \
      a0_ = fdot2f(bc(u_.x), w[4 * q_ + 0], a0_);             \
      a1_ = fdot2f(bc(u_.y), w[4 * q_ + 1], a1_);             \
      a2_ = fdot2f(bc(u_.z), w[4 * q_ + 2], a2_);             \
      a3_ = fdot2f(bc(u_.w), w[4 * q_ + 3], a3_);             \
    }                                                         \
    RES = (a0_ + a1_) + (a2_ + a3_);                          \
  } while (0)

__global__ __launch_bounds__(512, 4) void rnn_pipe(
    const unsigned int* __restrict__ pre0p, const float* __restrict__ Whh0,
    const float* __restrict__ Wih, const float* __restrict__ Whh,
    const float* __restrict__ bih, const float* __restrict__ bhh,
    const float* __restrict__ Wfc, const float* __restrict__ bfc,
    float* __restrict__ out) {
  const int tid  = threadIdx.x;
  const int lane = tid & 63;
  const int wv   = __builtin_amdgcn_readfirstlane(tid >> 6);  // scalar 0..7
  const int b    = blockIdx.x;

  // [layer][interval-slot][step-within-interval][lane]
  __shared__ __attribute__((aligned(16))) __fp16 hbuf[4][2][4][64];  // 4 KiB
  __shared__ float Pbuf[3][2][4][64];                                // 6 KiB

  // zero-init hbuf (h[t=-1] = 0): 4096 B = 1024 floats, blockDim = 512
  ((float*)hbuf)[tid]       = 0.f;
  ((float*)hbuf)[tid + 512] = 0.f;

  // role/weights per wave (wv scalar -> role/L/W scalar)
  const float* W;
  float bias = 0.f;
  int role, L;
  if (wv == 7) {
    role = 2; L = 3; W = Wfc; bias = bfc[lane];
  } else if ((wv & 1) == 0) {
    role = 0; L = wv >> 1;
    W = (L == 0) ? Whh0 : (Whh + (L - 1) * 4096);
    if (L > 0) bias = bih[(L - 1) * 64 + lane] + bhh[(L - 1) * 64 + lane];
  } else {
    role = 1; L = (wv + 1) >> 1;
    W = Wih + (L - 1) * 4096;
  }

  h2 w[32];
  const float2* wsrc = (const float2*)(W + lane * 64);
#pragma unroll
  for (int k = 0; k < 32; ++k) {
    float2 v = wsrc[k];
    w[k] = pk2(v.x, v.y);
  }

  const long rowbase = (long)b * T_STEPS;
  const unsigned int* pp = pre0p + (long)b * 512 * 64 + lane;  // paired pre0
  float* op = out + rowbase * 64 + lane;

  unsigned int pc0 = 0, pc1 = 0;  // pre pairs for t={4k..4k+3}
  if (wv == 0) { pc0 = pp[0]; pc1 = pp[64]; }

  __syncthreads();

#pragma unroll 1
  for (int k = 0; k < 256 + 7; ++k) {
    const unsigned kk = (unsigned)(k - wv);  // interval index for this wave
    const int rd = (k - 1) & 1;
    const int wr = k & 1;
    if (kk < 256u) {
      if (role == 0) {
        // 4 serial steps: t0 = 4*kk .. t0+3
        float p0_, p1_, p2_, p3_;
        if (L == 0) {
          h2 u0 = bc(pc0), u1 = bc(pc1);
          p0_ = (float)u0.x; p1_ = (float)u0.y;
          p2_ = (float)u1.x; p3_ = (float)u1.y;
          pp += 128;
          if (kk + 1 < 256u) { pc0 = pp[0]; pc1 = pp[64]; }  // prefetch
        } else {
          p0_ = Pbuf[L - 1][rd][0][lane];
          p1_ = Pbuf[L - 1][rd][1][lane];
          p2_ = Pbuf[L - 1][rd][2][lane];
          p3_ = Pbuf[L - 1][rd][3][lane];
        }
        float hv;
        GEMV64(hv, hbuf[L][rd][3], bias);     // h[t0-1] from prev interval
        float h0v = fast_tanh(hv + p0_);
        hbuf[L][wr][0][lane] = (__fp16)h0v;
        GEMV64(hv, hbuf[L][wr][0], bias);     // intra-wave readback
        float h1v = fast_tanh(hv + p1_);
        hbuf[L][wr][1][lane] = (__fp16)h1v;
        GEMV64(hv, hbuf[L][wr][1], bias);
        float h2v = fast_tanh(hv + p2_);
        hbuf[L][wr][2][lane] = (__fp16)h2v;
        GEMV64(hv, hbuf[L][wr][2], bias);
        float h3v = fast_tanh(hv + p3_);
        hbuf[L][wr][3][lane] = (__fp16)h3v;
      } else if (role == 1) {
        // 4 independent GEMVs: P_L[t] = Wih_L h_{L-1}[t]
        float q0, q1, q2, q3;
        GEMV64(q0, hbuf[L - 1][rd][0], 0.f);
        GEMV64(q1, hbuf[L - 1][rd][1], 0.f);
        GEMV64(q2, hbuf[L - 1][rd][2], 0.f);
        GEMV64(q3, hbuf[L - 1][rd][3], 0.f);
        Pbuf[L - 1][wr][0][lane] = q0;
        Pbuf[L - 1][wr][1][lane] = q1;
        Pbuf[L - 1][wr][2][lane] = q2;
        Pbuf[L - 1][wr][3][lane] = q3;
      } else {
        // 4 independent GEMVs: out[t] = Wfc h3[t] + bfc
        float q0, q1, q2, q3;
        GEMV64(q0, hbuf[3][rd][0], bias);
        GEMV64(q1, hbuf[3][rd][1], bias);
        GEMV64(q2, hbuf[3][rd][2], bias);
        GEMV64(q3, hbuf[3][rd][3], bias);
        op[0]   = q0;
        op[64]  = q1;
        op[128] = q2;
        op[192] = q3;
        op += 256;
      }
    }
    __syncthreads();  // uniform: every thread, every interval
  }
}

// ---------------------------------------------------------------------------
extern "C" void kernel_launch(void* const* d_in, const int* in_sizes, int n_in,
                              void* d_out, int out_size, void* d_ws,
                              size_t ws_size, hipStream_t stream) {
  const float* x    = (const float*)d_in[0];
  const float* Wih0 = (const float*)d_in[1];
  const float* Whh0 = (const float*)d_in[2];
  const float* bih0 = (const float*)d_in[3];
  const float* bhh0 = (const float*)d_in[4];
  const float* Wih  = (const float*)d_in[5];
  const float* Whh  = (const float*)d_in[6];
  const float* bih  = (const float*)d_in[7];
  const float* bhh  = (const float*)d_in[8];
  const float* Wfc  = (const float*)d_in[9];
  const float* bfc  = (const float*)d_in[10];
  float* out = (float*)d_out;

  const int B = in_sizes[0] / (T_STEPS * 52);  // 512
  const int R = B * T_STEPS;

  unsigned int* pre0p = (unsigned int*)d_ws;  // R/2 * 64 u32 = 64 MiB

  pre0_kernel<<<R / 64, 256, 0, stream>>>(x, Wih0, bih0, bhh0, pre0p);
  rnn_pipe<<<B, 512, 0, stream>>>(pre0p, Whh0, Wih, Whh, bih, bhh, Wfc, bfc,
                                  out);
}